// Round 5
// baseline (1238.175 us; speedup 1.0000x reference)
//
#include <hip/hip_runtime.h>
#include <math.h>

#define N_NODES 5000
#define IN_DIM  1280
#define HID     128
#define ALPHA   0.2f
#define NF4     20480000   // 5000*128*128/4 float4 elements of W1

typedef float f4v __attribute__((ext_vector_type(4)));

__device__ __forceinline__ float leaky(float v) { return v >= 0.f ? v : ALPHA * v; }

// ---------------- GEMM 1: hp[ky] = x @ W_in (split-K halves, no bias) ----------------
__global__ __launch_bounds__(256) void k_gemm_in(const float* __restrict__ x,
    const float* __restrict__ W, float* __restrict__ hp) {
  const int col  = threadIdx.x & 127;
  const int rg   = threadIdx.x >> 7;       // 0..1 -> rows rg*4..rg*4+3
  const int row0 = blockIdx.x * 8;         // 625 blocks
  const int kbase = blockIdx.y * 640;      // split-K: 2 halves
  __shared__ float xs[8][128];
  float acc[4] = {0.f,0.f,0.f,0.f};
  for (int k0 = 0; k0 < 640; k0 += 128) {
#pragma unroll
    for (int t = 0; t < 4; ++t) {
      int idx = threadIdx.x + t * 256;
      int r = idx >> 7, cc = idx & 127;
      xs[r][cc] = x[(size_t)(row0 + r) * IN_DIM + kbase + k0 + cc];
    }
    __syncthreads();
#pragma unroll 8
    for (int kq = 0; kq < 32; ++kq) {
      const int kk = kbase + k0 + kq * 4;
      const float w0 = W[(kk + 0) * HID + col];
      const float w1 = W[(kk + 1) * HID + col];
      const float w2 = W[(kk + 2) * HID + col];
      const float w3 = W[(kk + 3) * HID + col];
#pragma unroll
      for (int r = 0; r < 4; ++r) {
        const f4v xv = *reinterpret_cast<const f4v*>(&xs[rg * 4 + r][kq * 4]);
        acc[r] = fmaf(xv.x, w0, acc[r]);
        acc[r] = fmaf(xv.y, w1, acc[r]);
        acc[r] = fmaf(xv.z, w2, acc[r]);
        acc[r] = fmaf(xv.w, w3, acc[r]);
      }
    }
    __syncthreads();
  }
  float* o = hp + (size_t)blockIdx.y * N_NODES * HID;
#pragma unroll
  for (int r = 0; r < 4; ++r)
    o[(size_t)(row0 + rg * 4 + r) * HID + col] = acc[r];
}

// ------- GEMM 2: h = relu(hp0+hp1+b_in); xl = h@W_l + b_l ; xr = h@W_r + b_r -------
__global__ __launch_bounds__(256) void k_gemm_lr(const float* __restrict__ hp,
    const float* __restrict__ bin,
    const float* __restrict__ Wl, const float* __restrict__ bl,
    const float* __restrict__ Wr, const float* __restrict__ br,
    float* __restrict__ xl, float* __restrict__ xr) {
  const int col  = threadIdx.x & 127;
  const int rg   = threadIdx.x >> 7;       // 0..1 (4 rows each)
  const int row0 = blockIdx.x * 8;
  __shared__ float hs[8][128];
  const float* hp0 = hp;
  const float* hp1 = hp + (size_t)N_NODES * HID;
#pragma unroll
  for (int t = 0; t < 4; ++t) {
    int idx = threadIdx.x + t * 256;
    int r = idx >> 7, c = idx & 127;
    size_t g = (size_t)(row0 + r) * HID + c;
    hs[r][c] = fmaxf(hp0[g] + hp1[g] + bin[c], 0.f);
  }
  __syncthreads();
  float accl[4] = {0.f,0.f,0.f,0.f};
  float accr[4] = {0.f,0.f,0.f,0.f};
#pragma unroll 4
  for (int kq = 0; kq < 32; ++kq) {
    float wl0 = Wl[(kq*4+0)*HID + col], wr0 = Wr[(kq*4+0)*HID + col];
    float wl1 = Wl[(kq*4+1)*HID + col], wr1 = Wr[(kq*4+1)*HID + col];
    float wl2 = Wl[(kq*4+2)*HID + col], wr2 = Wr[(kq*4+2)*HID + col];
    float wl3 = Wl[(kq*4+3)*HID + col], wr3 = Wr[(kq*4+3)*HID + col];
#pragma unroll
    for (int r = 0; r < 4; ++r) {
      const f4v xv = *reinterpret_cast<const f4v*>(&hs[rg*4 + r][kq*4]);
      accl[r] = fmaf(xv.x, wl0, accl[r]); accr[r] = fmaf(xv.x, wr0, accr[r]);
      accl[r] = fmaf(xv.y, wl1, accl[r]); accr[r] = fmaf(xv.y, wr1, accr[r]);
      accl[r] = fmaf(xv.z, wl2, accl[r]); accr[r] = fmaf(xv.z, wr2, accr[r]);
      accl[r] = fmaf(xv.w, wl3, accl[r]); accr[r] = fmaf(xv.w, wr3, accr[r]);
    }
  }
  const float biasl = bl[col], biasr = br[col];
#pragma unroll
  for (int r = 0; r < 4; ++r) {
    int row = row0 + rg * 4 + r;
    xl[(size_t)row * HID + col] = accl[r] + biasl;
    xr[(size_t)row * HID + col] = accr[r] + biasr;
  }
}

// ---------------- CSR build: hist -> scan -> fill ----------------
__global__ __launch_bounds__(256) void k_hist(const int* __restrict__ ei, int E, int ET,
                                              unsigned* __restrict__ deg) {
  int e = blockIdx.x * blockDim.x + threadIdx.x;
  if (e >= ET) return;
  const int dst = (e < E) ? ei[E + e] : (e - E);
  atomicAdd(&deg[dst], 1u);
}

__global__ __launch_bounds__(256) void k_scan(const unsigned* __restrict__ deg,
    unsigned* __restrict__ off, unsigned* __restrict__ cursor,
    float* __restrict__ out128) {
  __shared__ unsigned part[256];
  const int t = threadIdx.x;
  if (t < HID) out128[t] = 0.f;          // zero the final accumulator here
  unsigned s = 0;
#pragma unroll
  for (int i = 0; i < 20; ++i) { int d = t * 20 + i; if (d < N_NODES) s += deg[d]; }
  part[t] = s;
  __syncthreads();
  for (int st = 1; st < 256; st <<= 1) {
    unsigned val = (t >= st) ? part[t - st] : 0u;
    __syncthreads();
    part[t] += val;
    __syncthreads();
  }
  unsigned run = (t == 0) ? 0u : part[t - 1];
  for (int i = 0; i < 20; ++i) {
    int d = t * 20 + i;
    if (d < N_NODES) { off[d] = run; cursor[d] = run; run += deg[d]; }
  }
}

__global__ __launch_bounds__(256) void k_fill(const int* __restrict__ ei, int E, int ET,
    unsigned* __restrict__ cursor, unsigned* __restrict__ csr) {
  int e = blockIdx.x * blockDim.x + threadIdx.x;
  if (e >= ET) return;
  const int src = (e < E) ? ei[e]     : (e - E);
  const int dst = (e < E) ? ei[E + e] : (e - E);
  unsigned pos = atomicAdd(&cursor[dst], 1u);
  csr[pos] = (unsigned)src;
}

// -------- per-dst single-pass online-softmax aggregation: v = leaky(GATv2 out) --------
__global__ __launch_bounds__(64) void k_agg(const float* __restrict__ xl,
    const float* __restrict__ xr, const float* __restrict__ att,
    const float* __restrict__ gb, const unsigned* __restrict__ off,
    const unsigned* __restrict__ deg, const unsigned* __restrict__ csr,
    float* __restrict__ v) {
  const int dst  = blockIdx.x;
  const int lane = threadIdx.x;                 // cols 2*lane, 2*lane+1
  const unsigned o  = off[dst];
  const unsigned dg = deg[dst];
  const float2 xr2 = *reinterpret_cast<const float2*>(&xr[(size_t)dst * HID + lane * 2]);
  const float2 at2 = *reinterpret_cast<const float2*>(&att[lane * 2]);
  float m = -INFINITY, s = 0.f;
  float2 acc = make_float2(0.f, 0.f);
  for (unsigned t = 0; t < dg; ++t) {
    const unsigned src = csr[o + t];
    const float2 xl2 = *reinterpret_cast<const float2*>(&xl[(size_t)src * HID + lane * 2]);
    float sa = leaky(xl2.x + xr2.x) * at2.x + leaky(xl2.y + xr2.y) * at2.y;
#pragma unroll
    for (int st = 1; st < 64; st <<= 1) sa += __shfl_xor(sa, st);
    if (sa > m) {            // wave-uniform branch (sa identical on all lanes)
      const float sc = __expf(m - sa);     // first iter: exp(-inf)=0
      s = s * sc + 1.f;
      acc.x = acc.x * sc + xl2.x;
      acc.y = acc.y * sc + xl2.y;
      m = sa;
    } else {
      const float ex = __expf(sa - m);
      s += ex;
      acc.x = fmaf(ex, xl2.x, acc.x);
      acc.y = fmaf(ex, xl2.y, acc.y);
    }
  }
  const float inv = 1.f / s;
  const float2 gb2 = *reinterpret_cast<const float2*>(&gb[lane * 2]);
  float2 r;
  r.x = leaky(fmaf(acc.x, inv, gb2.x));
  r.y = leaky(fmaf(acc.y, inv, gb2.y));
  *reinterpret_cast<float2*>(&v[(size_t)dst * HID + lane * 2]) = r;
}

// ---- out128[j] = sum_i v[i]*W1[i*128+j] : grid-wide LINEAR sweep of W1 ----
// 1024 blocks x 256 threads; thread t reads float4s t + k*262144 -> consecutive
// threads perfectly contiguous, whole machine advances as 8 linear fronts.
__global__ __launch_bounds__(256) void k_matvec(const float* __restrict__ v,
    const float* __restrict__ W1, float* __restrict__ out128) {
  const int tid = blockIdx.x * 256 + threadIdx.x;   // 0..262143
  const int NT  = 1024 * 256;                       // 262144 (== 0 mod 32)
  const f4v* W4 = reinterpret_cast<const f4v*>(W1);
  f4v acc = {0.f, 0.f, 0.f, 0.f};
#pragma unroll
  for (int o = 0; o < 10; ++o) {
    f4v  w[8]; float vv[8]; int idx[8]; bool ok[8];
#pragma unroll
    for (int u = 0; u < 8; ++u) {
      idx[u] = tid + (o * 8 + u) * NT;
      ok[u]  = idx[u] < NF4;
      if (ok[u]) w[u] = __builtin_nontemporal_load(&W4[idx[u]]);
    }
#pragma unroll
    for (int u = 0; u < 8; ++u) if (ok[u]) vv[u] = v[idx[u] >> 5];
#pragma unroll
    for (int u = 0; u < 8; ++u) if (ok[u]) {
      acc.x = fmaf(vv[u], w[u].x, acc.x);
      acc.y = fmaf(vv[u], w[u].y, acc.y);
      acc.z = fmaf(vv[u], w[u].z, acc.z);
      acc.w = fmaf(vv[u], w[u].w, acc.w);
    }
  }
  // col quad of thread = tid & 31 (stride NT*4 == 0 mod 128) — block reduce
  __shared__ float part[8][128];
  const int q = threadIdx.x & 31, rr = threadIdx.x >> 5;
  *reinterpret_cast<f4v*>(&part[rr][q * 4]) = acc;
  __syncthreads();
  if (rr == 0) {
    f4v s = {0.f, 0.f, 0.f, 0.f};
#pragma unroll
    for (int g = 0; g < 8; ++g) {
      const f4v p = *reinterpret_cast<const f4v*>(&part[g][q * 4]);
      s.x += p.x; s.y += p.y; s.z += p.z; s.w += p.w;
    }
    atomicAdd(&out128[q * 4 + 0], s.x);
    atomicAdd(&out128[q * 4 + 1], s.y);
    atomicAdd(&out128[q * 4 + 2], s.z);
    atomicAdd(&out128[q * 4 + 3], s.w);
  }
}

// y = relu(out128 + b1); out = y @ W2 + b2
__global__ void k_final(const float* __restrict__ out128, const float* __restrict__ b1,
                        const float* __restrict__ W2, const float* __restrict__ b2,
                        float* __restrict__ out) {
  const int j = threadIdx.x;   // 128 threads = 2 waves
  float y = fmaxf(out128[j] + b1[j], 0.f) * W2[j];
  __shared__ float red[2];
#pragma unroll
  for (int st = 32; st > 0; st >>= 1) y += __shfl_down(y, st);
  if ((j & 63) == 0) red[j >> 6] = y;
  __syncthreads();
  if (j == 0) out[0] = red[0] + red[1] + b2[0];
}

extern "C" void kernel_launch(void* const* d_in, const int* in_sizes, int n_in,
                              void* d_out, int out_size, void* d_ws, size_t ws_size,
                              hipStream_t stream) {
  const float* x    = (const float*)d_in[0];
  const int*   ei   = (const int*)  d_in[1];
  const float* W_in = (const float*)d_in[2];
  const float* b_in = (const float*)d_in[3];
  const float* W_l  = (const float*)d_in[4];
  const float* b_l  = (const float*)d_in[5];
  const float* W_r  = (const float*)d_in[6];
  const float* b_r  = (const float*)d_in[7];
  const float* att  = (const float*)d_in[8];
  const float* gb   = (const float*)d_in[9];
  const float* W1   = (const float*)d_in[10];
  const float* b1   = (const float*)d_in[11];
  const float* W2   = (const float*)d_in[12];
  const float* b2   = (const float*)d_in[13];
  float* out = (float*)d_out;

  const int E  = in_sizes[1] / 2;
  const int ET = E + N_NODES;

  float* ws = (float*)d_ws;
  float*    hp     = ws;                         // 2 * 640000 (split-K partials)
  float*    xl     = ws + 1280000;               // 640000
  float*    xr     = ws + 1920000;               // 640000
  float*    v      = ws + 2560000;               // 640000
  unsigned* deg    = (unsigned*)(ws + 3200000);  // 5000 (zeroed by memset)
  float*    out128 = ws + 3200000 + N_NODES;     // 128  (zeroed in k_scan)
  unsigned* off    = (unsigned*)(out128 + HID);  // 5000
  unsigned* cursor = off + N_NODES;              // 5000
  unsigned* csr    = cursor + N_NODES;           // ET

  hipMemsetAsync(deg, 0, (size_t)N_NODES * sizeof(unsigned), stream);

  k_gemm_in <<<dim3(N_NODES / 8, 2), 256, 0, stream>>>(x, W_in, hp);
  k_gemm_lr <<<N_NODES / 8, 256, 0, stream>>>(hp, b_in, W_l, b_l, W_r, b_r, xl, xr);
  k_hist    <<<(ET + 255) / 256, 256, 0, stream>>>(ei, E, ET, deg);
  k_scan    <<<1, 256, 0, stream>>>(deg, off, cursor, out128);
  k_fill    <<<(ET + 255) / 256, 256, 0, stream>>>(ei, E, ET, cursor, csr);
  k_agg     <<<N_NODES, 64, 0, stream>>>(xl, xr, att, gb, off, deg, csr, v);
  k_matvec  <<<1024, 256, 0, stream>>>(v, W1, out128);
  k_final   <<<1, 128, 0, stream>>>(out128, b1, W2, b2, out);
}

// Round 7
// 684.631 us; speedup vs baseline: 1.8085x; 1.8085x over previous
//
#include <hip/hip_runtime.h>
#include <math.h>

#define N_NODES 5000
#define IN_DIM  1280
#define HID     128
#define ALPHA   0.2f
#define NT_MV   256000     // threads in k_matvec grid; NF4 = 80 * NT_MV exactly

typedef float f4v __attribute__((ext_vector_type(4)));

__device__ __forceinline__ float leaky(float v) { return v >= 0.f ? v : ALPHA * v; }

// ---------------- GEMM 1: hp[ky] = x @ W_in (split-K halves, no bias) ----------------
__global__ __launch_bounds__(256) void k_gemm_in(const float* __restrict__ x,
    const float* __restrict__ W, float* __restrict__ hp) {
  const int col  = threadIdx.x & 127;
  const int rg   = threadIdx.x >> 7;       // 0..1 -> rows rg*4..rg*4+3
  const int row0 = blockIdx.x * 8;         // 625 blocks
  const int kbase = blockIdx.y * 640;      // split-K: 2 halves
  __shared__ float xs[8][128];
  float acc[4] = {0.f,0.f,0.f,0.f};
  for (int k0 = 0; k0 < 640; k0 += 128) {
#pragma unroll
    for (int t = 0; t < 4; ++t) {
      int idx = threadIdx.x + t * 256;
      int r = idx >> 7, cc = idx & 127;
      xs[r][cc] = x[(size_t)(row0 + r) * IN_DIM + kbase + k0 + cc];
    }
    __syncthreads();
#pragma unroll 8
    for (int kq = 0; kq < 32; ++kq) {
      const int kk = kbase + k0 + kq * 4;
      const float w0 = W[(kk + 0) * HID + col];
      const float w1 = W[(kk + 1) * HID + col];
      const float w2 = W[(kk + 2) * HID + col];
      const float w3 = W[(kk + 3) * HID + col];
#pragma unroll
      for (int r = 0; r < 4; ++r) {
        const f4v xv = *reinterpret_cast<const f4v*>(&xs[rg * 4 + r][kq * 4]);
        acc[r] = fmaf(xv.x, w0, acc[r]);
        acc[r] = fmaf(xv.y, w1, acc[r]);
        acc[r] = fmaf(xv.z, w2, acc[r]);
        acc[r] = fmaf(xv.w, w3, acc[r]);
      }
    }
    __syncthreads();
  }
  float* o = hp + (size_t)blockIdx.y * N_NODES * HID;
#pragma unroll
  for (int r = 0; r < 4; ++r)
    o[(size_t)(row0 + rg * 4 + r) * HID + col] = acc[r];
}

// ------- GEMM 2: h = relu(hp0+hp1+b_in); xl = h@W_l + b_l ; xr = h@W_r + b_r -------
__global__ __launch_bounds__(256) void k_gemm_lr(const float* __restrict__ hp,
    const float* __restrict__ bin,
    const float* __restrict__ Wl, const float* __restrict__ bl,
    const float* __restrict__ Wr, const float* __restrict__ br,
    float* __restrict__ xl, float* __restrict__ xr) {
  const int col  = threadIdx.x & 127;
  const int rg   = threadIdx.x >> 7;       // 0..1 (4 rows each)
  const int row0 = blockIdx.x * 8;
  __shared__ float hs[8][128];
  const float* hp0 = hp;
  const float* hp1 = hp + (size_t)N_NODES * HID;
#pragma unroll
  for (int t = 0; t < 4; ++t) {
    int idx = threadIdx.x + t * 256;
    int r = idx >> 7, c = idx & 127;
    size_t g = (size_t)(row0 + r) * HID + c;
    hs[r][c] = fmaxf(hp0[g] + hp1[g] + bin[c], 0.f);
  }
  __syncthreads();
  float accl[4] = {0.f,0.f,0.f,0.f};
  float accr[4] = {0.f,0.f,0.f,0.f};
#pragma unroll 4
  for (int kq = 0; kq < 32; ++kq) {
    float wl0 = Wl[(kq*4+0)*HID + col], wr0 = Wr[(kq*4+0)*HID + col];
    float wl1 = Wl[(kq*4+1)*HID + col], wr1 = Wr[(kq*4+1)*HID + col];
    float wl2 = Wl[(kq*4+2)*HID + col], wr2 = Wr[(kq*4+2)*HID + col];
    float wl3 = Wl[(kq*4+3)*HID + col], wr3 = Wr[(kq*4+3)*HID + col];
#pragma unroll
    for (int r = 0; r < 4; ++r) {
      const f4v xv = *reinterpret_cast<const f4v*>(&hs[rg*4 + r][kq*4]);
      accl[r] = fmaf(xv.x, wl0, accl[r]); accr[r] = fmaf(xv.x, wr0, accr[r]);
      accl[r] = fmaf(xv.y, wl1, accl[r]); accr[r] = fmaf(xv.y, wr1, accr[r]);
      accl[r] = fmaf(xv.z, wl2, accl[r]); accr[r] = fmaf(xv.z, wr2, accr[r]);
      accl[r] = fmaf(xv.w, wl3, accl[r]); accr[r] = fmaf(xv.w, wr3, accr[r]);
    }
  }
  const float biasl = bl[col], biasr = br[col];
#pragma unroll
  for (int r = 0; r < 4; ++r) {
    int row = row0 + rg * 4 + r;
    xl[(size_t)row * HID + col] = accl[r] + biasl;
    xr[(size_t)row * HID + col] = accr[r] + biasr;
  }
}

// ---------------- CSR build: hist -> scan -> fill ----------------
__global__ __launch_bounds__(256) void k_hist(const int* __restrict__ ei, int E, int ET,
                                              unsigned* __restrict__ deg) {
  int e = blockIdx.x * blockDim.x + threadIdx.x;
  if (e >= ET) return;
  const int dst = (e < E) ? ei[E + e] : (e - E);
  atomicAdd(&deg[dst], 1u);
}

__global__ __launch_bounds__(256) void k_scan(const unsigned* __restrict__ deg,
    unsigned* __restrict__ off, unsigned* __restrict__ cursor,
    float* __restrict__ out128) {
  __shared__ unsigned part[256];
  const int t = threadIdx.x;
  if (t < HID) out128[t] = 0.f;          // zero the final accumulator here
  unsigned s = 0;
#pragma unroll
  for (int i = 0; i < 20; ++i) { int d = t * 20 + i; if (d < N_NODES) s += deg[d]; }
  part[t] = s;
  __syncthreads();
  for (int st = 1; st < 256; st <<= 1) {
    unsigned val = (t >= st) ? part[t - st] : 0u;
    __syncthreads();
    part[t] += val;
    __syncthreads();
  }
  unsigned run = (t == 0) ? 0u : part[t - 1];
  for (int i = 0; i < 20; ++i) {
    int d = t * 20 + i;
    if (d < N_NODES) { off[d] = run; cursor[d] = run; run += deg[d]; }
  }
}

__global__ __launch_bounds__(256) void k_fill(const int* __restrict__ ei, int E, int ET,
    unsigned* __restrict__ cursor, unsigned* __restrict__ csr) {
  int e = blockIdx.x * blockDim.x + threadIdx.x;
  if (e >= ET) return;
  const int src = (e < E) ? ei[e]     : (e - E);
  const int dst = (e < E) ? ei[E + e] : (e - E);
  unsigned pos = atomicAdd(&cursor[dst], 1u);
  csr[pos] = (unsigned)src;
}

// -------- per-dst single-pass online-softmax aggregation: v = leaky(GATv2 out) --------
__global__ __launch_bounds__(64) void k_agg(const float* __restrict__ xl,
    const float* __restrict__ xr, const float* __restrict__ att,
    const float* __restrict__ gb, const unsigned* __restrict__ off,
    const unsigned* __restrict__ deg, const unsigned* __restrict__ csr,
    float* __restrict__ v) {
  const int dst  = blockIdx.x;
  const int lane = threadIdx.x;                 // cols 2*lane, 2*lane+1
  const unsigned o  = off[dst];
  const unsigned dg = deg[dst];
  const float2 xr2 = *reinterpret_cast<const float2*>(&xr[(size_t)dst * HID + lane * 2]);
  const float2 at2 = *reinterpret_cast<const float2*>(&att[lane * 2]);
  float m = -INFINITY, s = 0.f;
  float2 acc = make_float2(0.f, 0.f);
  for (unsigned t = 0; t < dg; ++t) {
    const unsigned src = csr[o + t];
    const float2 xl2 = *reinterpret_cast<const float2*>(&xl[(size_t)src * HID + lane * 2]);
    float sa = leaky(xl2.x + xr2.x) * at2.x + leaky(xl2.y + xr2.y) * at2.y;
#pragma unroll
    for (int st = 1; st < 64; st <<= 1) sa += __shfl_xor(sa, st);
    if (sa > m) {            // wave-uniform branch (sa identical on all lanes)
      const float sc = __expf(m - sa);     // first iter: exp(-inf)=0
      s = s * sc + 1.f;
      acc.x = acc.x * sc + xl2.x;
      acc.y = acc.y * sc + xl2.y;
      m = sa;
    } else {
      const float ex = __expf(sa - m);
      s += ex;
      acc.x = fmaf(ex, xl2.x, acc.x);
      acc.y = fmaf(ex, xl2.y, acc.y);
    }
  }
  const float inv = 1.f / s;
  const float2 gb2 = *reinterpret_cast<const float2*>(&gb[lane * 2]);
  float2 r;
  r.x = leaky(fmaf(acc.x, inv, gb2.x));
  r.y = leaky(fmaf(acc.y, inv, gb2.y));
  *reinterpret_cast<float2*>(&v[(size_t)dst * HID + lane * 2]) = r;
}

// ---- out128[j] = sum_i v[i]*W1[i*128+j] : grid-wide LINEAR sweep, no spills ----
// 1000 blocks x 256 = 256000 threads; thread t reads float4 t + k*256000,
// k = 0..79 (exact). Consecutive threads contiguous across the whole machine.
// Stride 256000 % 32 == 0 -> col quad of thread is invariant (= tid & 31).
__global__ __launch_bounds__(256) void k_matvec(const float* __restrict__ v,
    const float* __restrict__ W1, float* __restrict__ out128) {
  const int tid = blockIdx.x * 256 + threadIdx.x;
  const f4v* W4 = reinterpret_cast<const f4v*>(W1);
  f4v acc = {0.f, 0.f, 0.f, 0.f};
  int idx = tid;
#pragma unroll 2
  for (int o = 0; o < 20; ++o) {
    const f4v w0 = __builtin_nontemporal_load(&W4[idx]);
    const f4v w1 = __builtin_nontemporal_load(&W4[idx + NT_MV]);
    const f4v w2 = __builtin_nontemporal_load(&W4[idx + 2 * NT_MV]);
    const f4v w3 = __builtin_nontemporal_load(&W4[idx + 3 * NT_MV]);
    const float v0 = v[idx >> 5];
    const float v1 = v[(idx + NT_MV) >> 5];
    const float v2 = v[(idx + 2 * NT_MV) >> 5];
    const float v3 = v[(idx + 3 * NT_MV) >> 5];
    acc.x = fmaf(v0, w0.x, acc.x); acc.y = fmaf(v0, w0.y, acc.y);
    acc.z = fmaf(v0, w0.z, acc.z); acc.w = fmaf(v0, w0.w, acc.w);
    acc.x = fmaf(v1, w1.x, acc.x); acc.y = fmaf(v1, w1.y, acc.y);
    acc.z = fmaf(v1, w1.z, acc.z); acc.w = fmaf(v1, w1.w, acc.w);
    acc.x = fmaf(v2, w2.x, acc.x); acc.y = fmaf(v2, w2.y, acc.y);
    acc.z = fmaf(v2, w2.z, acc.z); acc.w = fmaf(v2, w2.w, acc.w);
    acc.x = fmaf(v3, w3.x, acc.x); acc.y = fmaf(v3, w3.y, acc.y);
    acc.z = fmaf(v3, w3.z, acc.z); acc.w = fmaf(v3, w3.w, acc.w);
    idx += 4 * NT_MV;
  }
  __shared__ float part[8][128];
  const int q = threadIdx.x & 31, rr = threadIdx.x >> 5;
  *reinterpret_cast<f4v*>(&part[rr][q * 4]) = acc;
  __syncthreads();
  if (rr == 0) {
    f4v s = {0.f, 0.f, 0.f, 0.f};
#pragma unroll
    for (int g = 0; g < 8; ++g) {
      const f4v p = *reinterpret_cast<const f4v*>(&part[g][q * 4]);
      s.x += p.x; s.y += p.y; s.z += p.z; s.w += p.w;
    }
    atomicAdd(&out128[q * 4 + 0], s.x);
    atomicAdd(&out128[q * 4 + 1], s.y);
    atomicAdd(&out128[q * 4 + 2], s.z);
    atomicAdd(&out128[q * 4 + 3], s.w);
  }
}

// y = relu(out128 + b1); out = y @ W2 + b2
__global__ void k_final(const float* __restrict__ out128, const float* __restrict__ b1,
                        const float* __restrict__ W2, const float* __restrict__ b2,
                        float* __restrict__ out) {
  const int j = threadIdx.x;   // 128 threads = 2 waves
  float y = fmaxf(out128[j] + b1[j], 0.f) * W2[j];
  __shared__ float red[2];
#pragma unroll
  for (int st = 32; st > 0; st >>= 1) y += __shfl_down(y, st);
  if ((j & 63) == 0) red[j >> 6] = y;
  __syncthreads();
  if (j == 0) out[0] = red[0] + red[1] + b2[0];
}

extern "C" void kernel_launch(void* const* d_in, const int* in_sizes, int n_in,
                              void* d_out, int out_size, void* d_ws, size_t ws_size,
                              hipStream_t stream) {
  const float* x    = (const float*)d_in[0];
  const int*   ei   = (const int*)  d_in[1];
  const float* W_in = (const float*)d_in[2];
  const float* b_in = (const float*)d_in[3];
  const float* W_l  = (const float*)d_in[4];
  const float* b_l  = (const float*)d_in[5];
  const float* W_r  = (const float*)d_in[6];
  const float* b_r  = (const float*)d_in[7];
  const float* att  = (const float*)d_in[8];
  const float* gb   = (const float*)d_in[9];
  const float* W1   = (const float*)d_in[10];
  const float* b1   = (const float*)d_in[11];
  const float* W2   = (const float*)d_in[12];
  const float* b2   = (const float*)d_in[13];
  float* out = (float*)d_out;

  const int E  = in_sizes[1] / 2;
  const int ET = E + N_NODES;

  float* ws = (float*)d_ws;
  float*    hp     = ws;                         // 2 * 640000 (split-K partials)
  float*    xl     = ws + 1280000;               // 640000
  float*    xr     = ws + 1920000;               // 640000
  float*    v      = ws + 2560000;               // 640000
  unsigned* deg    = (unsigned*)(ws + 3200000);  // 5000 (zeroed by memset)
  float*    out128 = ws + 3200000 + N_NODES;     // 128  (zeroed in k_scan)
  unsigned* off    = (unsigned*)(out128 + HID);  // 5000
  unsigned* cursor = off + N_NODES;              // 5000
  unsigned* csr    = cursor + N_NODES;           // ET

  hipMemsetAsync(deg, 0, (size_t)N_NODES * sizeof(unsigned), stream);

  k_gemm_in <<<dim3(N_NODES / 8, 2), 256, 0, stream>>>(x, W_in, hp);
  k_gemm_lr <<<N_NODES / 8, 256, 0, stream>>>(hp, b_in, W_l, b_l, W_r, b_r, xl, xr);
  k_hist    <<<(ET + 255) / 256, 256, 0, stream>>>(ei, E, ET, deg);
  k_scan    <<<1, 256, 0, stream>>>(deg, off, cursor, out128);
  k_fill    <<<(ET + 255) / 256, 256, 0, stream>>>(ei, E, ET, cursor, csr);
  k_agg     <<<N_NODES, 64, 0, stream>>>(xl, xr, att, gb, off, deg, csr, v);
  k_matvec  <<<1000, 256, 0, stream>>>(v, W1, out128);
  k_final   <<<1, 128, 0, stream>>>(out128, b1, W2, b2, out);
}